// Round 1
// baseline (265.621 us; speedup 1.0000x reference)
//
#include <hip/hip_runtime.h>

#define DH 128

typedef __bf16 bf16x8 __attribute__((ext_vector_type(8)));
typedef float f32x4 __attribute__((ext_vector_type(4)));

__device__ __forceinline__ ushort f2b(float f) {
  union { float f; unsigned u; } c; c.f = f;
  unsigned u = c.u;
  unsigned r = (u + 0x7fffu + ((u >> 16) & 1u)) >> 16;
  return (ushort)r;
}
__device__ __forceinline__ float b2f_lo(unsigned v) {
  union { unsigned u; float f; } c; c.u = v << 16;
  return c.f;
}
__device__ __forceinline__ float b2f_hi(unsigned v) {
  union { unsigned u; float f; } c; c.u = v & 0xffff0000u;
  return c.f;
}

// ---- convert f32 -> bf16, 8 elems/thread ----
__global__ void k_convert(const float* __restrict__ x, ushort* __restrict__ xb, long n8) {
  long i = (long)blockIdx.x * blockDim.x + threadIdx.x;
  if (i >= n8) return;
  const float4* p = (const float4*)x + i * 2;
  float4 a = p[0], b = p[1];
  uint4 o;
  o.x = (unsigned)f2b(a.x) | ((unsigned)f2b(a.y) << 16);
  o.y = (unsigned)f2b(a.z) | ((unsigned)f2b(a.w) << 16);
  o.z = (unsigned)f2b(b.x) | ((unsigned)f2b(b.y) << 16);
  o.w = (unsigned)f2b(b.z) | ((unsigned)f2b(b.w) << 16);
  ((uint4*)xb)[i] = o;
}

// ---- pack combined [Wself;Wneigh] (256x128) into MFMA B-fragment order ----
// Wp[((s*8+cb)*64+lane)*8 + j] = W[k][col], col = cb*16 + (lane&15), k = s*32 + (lane>>4)*8 + j
__global__ void k_pack(const float* __restrict__ Wself, const float* __restrict__ Wneigh,
                       ushort* __restrict__ Wp) {
  int idx = blockIdx.x * 256 + threadIdx.x;
  if (idx >= 8 * 8 * 64 * 8) return;
  int j = idx & 7;
  int lane = (idx >> 3) & 63;
  int cb = (idx >> 9) & 7;
  int s = (idx >> 12) & 7;
  int col = cb * 16 + (lane & 15);
  int k = s * 32 + ((lane >> 4) * 8) + j;
  float v = (k < 128) ? Wself[k * 128 + col] : Wneigh[(k - 128) * 128 + col];
  Wp[idx] = f2b(v);
}

// ---- degree histogram ----
__global__ void k_hist(const int* __restrict__ dst, int* __restrict__ deg, int E) {
  int e = blockIdx.x * 256 + threadIdx.x;
  if (e < E) atomicAdd(&deg[dst[e]], 1);
}

// ---- block-level inclusive scan (1024/block) ----
__global__ void k_scan1(const int* __restrict__ deg, int* __restrict__ rowptr,
                        int* __restrict__ bsum, int N) {
  __shared__ int s[1024];
  int t = threadIdx.x, i = blockIdx.x * 1024 + t;
  int v = (i < N) ? deg[i] : 0;
  s[t] = v;
  __syncthreads();
  for (int off = 1; off < 1024; off <<= 1) {
    int u = (t >= off) ? s[t - off] : 0;
    __syncthreads();
    s[t] += u;
    __syncthreads();
  }
  if (i < N) rowptr[i + 1] = s[t];
  if (t == 1023) bsum[blockIdx.x] = s[1023];
}

__global__ void k_scan2(int* bsum, int nb) {
  if (threadIdx.x == 0 && blockIdx.x == 0) {
    int run = 0;
    for (int i = 0; i < nb; ++i) { int v = bsum[i]; bsum[i] = run; run += v; }
  }
}

__global__ void k_scan3(int* __restrict__ rowptr, const int* __restrict__ bsum, int N) {
  int i = blockIdx.x * 1024 + threadIdx.x;
  if (i == 0) rowptr[0] = 0;
  if (i < N) rowptr[i + 1] += bsum[blockIdx.x];
}

// ---- cursor copy + invdeg ----
__global__ void k_prep(const int* __restrict__ rowptr, const int* __restrict__ deg,
                       int* __restrict__ cursor, float* __restrict__ invdeg, int N) {
  int i = blockIdx.x * 256 + threadIdx.x;
  if (i < N) {
    cursor[i] = rowptr[i];
    invdeg[i] = 1.0f / fmaxf((float)deg[i], 1.0f);
  }
}

// ---- CSR fill (atomic cursor) ----
__global__ void k_fill(const int* __restrict__ src, const int* __restrict__ dst,
                       int* __restrict__ cursor, int* __restrict__ colsrc, int E) {
  int e = blockIdx.x * 256 + threadIdx.x;
  if (e < E) {
    int d = dst[e];
    int pos = atomicAdd(&cursor[d], 1);
    colsrc[pos] = src[e];
  }
}

// ---- gather aggregation: mean of in-neighbor rows, bf16 in/out, f32 accum ----
// 256 threads = 8 groups of 32 lanes; group handles one node; lane covers 4 feats (8B)
__global__ void k_aggregate(const ushort* __restrict__ feat, const int* __restrict__ rowptr,
                            const int* __restrict__ colsrc, const float* __restrict__ invdeg,
                            ushort* __restrict__ out, int N) {
  int g = threadIdx.x >> 5, l = threadIdx.x & 31;
  int node = blockIdx.x * 8 + g;
  if (node >= N) return;
  int beg = rowptr[node], end = rowptr[node + 1];
  float a0 = 0.f, a1 = 0.f, a2 = 0.f, a3 = 0.f;
  for (int e = beg; e < end; ++e) {
    int s = colsrc[e];
    uint2 v = *(const uint2*)(feat + (size_t)s * DH + l * 4);
    a0 += b2f_lo(v.x); a1 += b2f_hi(v.x);
    a2 += b2f_lo(v.y); a3 += b2f_hi(v.y);
  }
  float sc = invdeg[node];
  uint2 o;
  o.x = (unsigned)f2b(a0 * sc) | ((unsigned)f2b(a1 * sc) << 16);
  o.y = (unsigned)f2b(a2 * sc) | ((unsigned)f2b(a3 * sc) << 16);
  *(uint2*)(out + (size_t)node * DH + l * 4) = o;
}

// ---- GEMM: out[i][:] = self[i]@Wself + neigh[i]@Wneigh + b, optional relu ----
// K=256 combined (ksteps 0-3 from self, 4-7 from neigh). 4 waves x 16 rows x 128 cols.
template <int RELU, int OUTF32>
__global__ void k_gemm(const ushort* __restrict__ selfb, const ushort* __restrict__ neighb,
                       const ushort* __restrict__ Wp, const float* __restrict__ bias,
                       void* __restrict__ outp, int M) {
  int wave = threadIdx.x >> 6, lane = threadIdx.x & 63;
  int rowA = blockIdx.x * 64 + wave * 16 + (lane & 15);
  int kq = lane >> 4;
  bool valid = rowA < M;
  size_t abase = (size_t)rowA * DH + kq * 8;
  f32x4 acc[8] = {};
#pragma unroll
  for (int hf = 0; hf < 2; ++hf) {
    const ushort* S = hf ? neighb : selfb;
#pragma unroll
    for (int ks = 0; ks < 4; ++ks) {
      bf16x8 a = {};
      if (valid) a = __builtin_bit_cast(bf16x8, *(const uint4*)(S + abase + ks * 32));
      int sg = hf * 4 + ks;
      const ushort* wp = Wp + sg * 4096 + lane * 8;
#pragma unroll
      for (int cb = 0; cb < 8; ++cb) {
        bf16x8 b = __builtin_bit_cast(bf16x8, *(const uint4*)(wp + cb * 512));
        acc[cb] = __builtin_amdgcn_mfma_f32_16x16x32_bf16(a, b, acc[cb], 0, 0, 0);
      }
    }
  }
  // C/D layout: col = lane&15, row = (lane>>4)*4 + reg
  int col = lane & 15;
  int row0 = blockIdx.x * 64 + wave * 16 + (lane >> 4) * 4;
#pragma unroll
  for (int cb = 0; cb < 8; ++cb) {
    float bv = bias[cb * 16 + col];
#pragma unroll
    for (int j = 0; j < 4; ++j) {
      int rr = row0 + j;
      if (rr < M) {
        float v = acc[cb][j] + bv;
        if (RELU) v = fmaxf(v, 0.f);
        if (OUTF32)
          ((float*)outp)[(size_t)rr * DH + cb * 16 + col] = v;
        else
          ((ushort*)outp)[(size_t)rr * DH + cb * 16 + col] = f2b(v);
      }
    }
  }
}

extern "C" void kernel_launch(void* const* d_in, const int* in_sizes, int n_in,
                              void* d_out, int out_size, void* d_ws, size_t ws_size,
                              hipStream_t stream) {
  const float* x = (const float*)d_in[0];
  const int* src = (const int*)d_in[1];
  const int* dst = (const int*)d_in[2];
  const float* Wself1 = (const float*)d_in[3];
  const float* Wneigh1 = (const float*)d_in[4];
  const float* b1 = (const float*)d_in[5];
  const float* Wself2 = (const float*)d_in[6];
  const float* Wneigh2 = (const float*)d_in[7];
  const float* b2 = (const float*)d_in[8];
  int N = in_sizes[0] / DH;
  int E = in_sizes[1];

  char* w = (char*)d_ws;
  auto alloc = [&](size_t bytes) {
    char* p = w;
    w += (bytes + 255) & ~(size_t)255;
    return p;
  };
  ushort* xb = (ushort*)alloc((size_t)N * DH * 2);
  ushort* hb = (ushort*)alloc((size_t)N * DH * 2);
  ushort* nb = (ushort*)alloc((size_t)N * DH * 2);
  ushort* Wp1 = (ushort*)alloc(32768 * 2);
  ushort* Wp2 = (ushort*)alloc(32768 * 2);
  int* deg = (int*)alloc((size_t)N * 4);
  int* rowptr = (int*)alloc((size_t)(N + 1) * 4);
  int* cursor = (int*)alloc((size_t)N * 4);
  float* invdeg = (float*)alloc((size_t)N * 4);
  int* colsrc = (int*)alloc((size_t)E * 4);
  int* bsum = (int*)alloc(4096);

  hipMemsetAsync(deg, 0, (size_t)N * 4, stream);

  long n8 = (long)N * DH / 8;
  k_convert<<<(int)((n8 + 255) / 256), 256, 0, stream>>>(x, xb, n8);
  k_pack<<<128, 256, 0, stream>>>(Wself1, Wneigh1, Wp1);
  k_pack<<<128, 256, 0, stream>>>(Wself2, Wneigh2, Wp2);
  k_hist<<<(E + 255) / 256, 256, 0, stream>>>(dst, deg, E);
  int nb1k = (N + 1023) / 1024;
  k_scan1<<<nb1k, 1024, 0, stream>>>(deg, rowptr, bsum, N);
  k_scan2<<<1, 64, 0, stream>>>(bsum, nb1k);
  k_scan3<<<nb1k, 1024, 0, stream>>>(rowptr, bsum, N);
  k_prep<<<(N + 255) / 256, 256, 0, stream>>>(rowptr, deg, cursor, invdeg, N);
  k_fill<<<(E + 255) / 256, 256, 0, stream>>>(src, dst, cursor, colsrc, E);

  int aggb = (N + 7) / 8;
  int gb = (N + 63) / 64;
  // layer 1
  k_aggregate<<<aggb, 256, 0, stream>>>(xb, rowptr, colsrc, invdeg, nb, N);
  k_gemm<1, 0><<<gb, 256, 0, stream>>>(xb, nb, Wp1, b1, hb, N);
  // layer 2
  k_aggregate<<<aggb, 256, 0, stream>>>(hb, rowptr, colsrc, invdeg, nb, N);
  k_gemm<0, 1><<<gb, 256, 0, stream>>>(hb, nb, Wp2, b2, d_out, N);
}

// Round 2
// 205.010 us; speedup vs baseline: 1.2957x; 1.2957x over previous
//
#include <hip/hip_runtime.h>

#define DH 128

typedef __bf16 bf16x8 __attribute__((ext_vector_type(8)));
typedef float f32x4 __attribute__((ext_vector_type(4)));

__device__ __forceinline__ ushort f2b(float f) {
  union { float f; unsigned u; } c; c.f = f;
  unsigned u = c.u;
  unsigned r = (u + 0x7fffu + ((u >> 16) & 1u)) >> 16;
  return (ushort)r;
}
__device__ __forceinline__ float b2f_lo(unsigned v) {
  union { unsigned u; float f; } c; c.u = v << 16;
  return c.f;
}
__device__ __forceinline__ float b2f_hi(unsigned v) {
  union { unsigned u; float f; } c; c.u = v & 0xffff0000u;
  return c.f;
}

// ---- convert f32 -> bf16, 8 elems/thread ----
__global__ void k_convert(const float* __restrict__ x, ushort* __restrict__ xb, long n8) {
  long i = (long)blockIdx.x * blockDim.x + threadIdx.x;
  if (i >= n8) return;
  const float4* p = (const float4*)x + i * 2;
  float4 a = p[0], b = p[1];
  uint4 o;
  o.x = (unsigned)f2b(a.x) | ((unsigned)f2b(a.y) << 16);
  o.y = (unsigned)f2b(a.z) | ((unsigned)f2b(a.w) << 16);
  o.z = (unsigned)f2b(b.x) | ((unsigned)f2b(b.y) << 16);
  o.w = (unsigned)f2b(b.z) | ((unsigned)f2b(b.w) << 16);
  ((uint4*)xb)[i] = o;
}

// ---- pack both layer weights [Wself;Wneigh] (256x128) into MFMA B-fragment order ----
// Wp[((s*8+cb)*64+lane)*8 + j] = W[k][col], col = cb*16 + (lane&15), k = s*32 + (lane>>4)*8 + j
__global__ void k_pack(const float* __restrict__ Ws1, const float* __restrict__ Wn1,
                       const float* __restrict__ Ws2, const float* __restrict__ Wn2,
                       ushort* __restrict__ Wp1, ushort* __restrict__ Wp2) {
  int idx = blockIdx.x * 256 + threadIdx.x;
  if (idx >= 2 * 8 * 8 * 64 * 8) return;
  int layer = idx >> 15;
  int t = idx & 32767;
  int j = t & 7;
  int lane = (t >> 3) & 63;
  int cb = (t >> 9) & 7;
  int s = (t >> 12) & 7;
  int col = cb * 16 + (lane & 15);
  int k = s * 32 + ((lane >> 4) * 8) + j;
  const float* Wself = layer ? Ws2 : Ws1;
  const float* Wneigh = layer ? Wn2 : Wn1;
  float v = (k < 128) ? Wself[k * 128 + col] : Wneigh[(k - 128) * 128 + col];
  (layer ? Wp2 : Wp1)[t] = f2b(v);
}

// ---- degree histogram ----
__global__ void k_hist(const int* __restrict__ dst, int* __restrict__ deg, int E) {
  int e = blockIdx.x * 256 + threadIdx.x;
  if (e < E) atomicAdd(&deg[dst[e]], 1);
}

// ---- block-level inclusive scan (1024/block) ----
__global__ void k_scan1(const int* __restrict__ deg, int* __restrict__ rowptr,
                        int* __restrict__ bsum, int N) {
  __shared__ int s[1024];
  int t = threadIdx.x, i = blockIdx.x * 1024 + t;
  int v = (i < N) ? deg[i] : 0;
  s[t] = v;
  __syncthreads();
  for (int off = 1; off < 1024; off <<= 1) {
    int u = (t >= off) ? s[t - off] : 0;
    __syncthreads();
    s[t] += u;
    __syncthreads();
  }
  if (i < N) rowptr[i + 1] = s[t];
  if (t == 1023) bsum[blockIdx.x] = s[1023];
}

// ---- exclusive scan of block sums: one wave, shfl scan (nb <= 64 fast path) ----
__global__ void k_scan2(int* bsum, int nb) {
  if (nb <= 64) {
    int l = threadIdx.x;
    int v = (l < nb) ? bsum[l] : 0;
    for (int off = 1; off < 64; off <<= 1) {
      int u = __shfl_up(v, off);
      if (l >= off) v += u;
    }
    int ex = __shfl_up(v, 1);
    if (l == 0) ex = 0;
    if (l < nb) bsum[l] = ex;
  } else if (threadIdx.x == 0) {
    int run = 0;
    for (int i = 0; i < nb; ++i) { int v = bsum[i]; bsum[i] = run; run += v; }
  }
}

// ---- add block offsets + emit cursor (=rowptr[i]) and invdeg ----
__global__ void k_scan3(int* __restrict__ rowptr, const int* __restrict__ bsum,
                        const int* __restrict__ deg, int* __restrict__ cursor,
                        float* __restrict__ invdeg, int N) {
  int i = blockIdx.x * 1024 + threadIdx.x;
  if (i == 0) rowptr[0] = 0;
  if (i < N) {
    int d = deg[i];
    int inc = rowptr[i + 1] + bsum[blockIdx.x];
    rowptr[i + 1] = inc;
    cursor[i] = inc - d;
    invdeg[i] = 1.0f / fmaxf((float)d, 1.0f);
  }
}

// ---- CSR fill (atomic cursor) ----
__global__ void k_fill(const int* __restrict__ src, const int* __restrict__ dst,
                       int* __restrict__ cursor, int* __restrict__ colsrc, int E) {
  int e = blockIdx.x * 256 + threadIdx.x;
  if (e < E) {
    int d = dst[e];
    int pos = atomicAdd(&cursor[d], 1);
    colsrc[pos] = src[e];
  }
}

__device__ __forceinline__ void acc8(float* a, uint4 v) {
  a[0] += b2f_lo(v.x); a[1] += b2f_hi(v.x);
  a[2] += b2f_lo(v.y); a[3] += b2f_hi(v.y);
  a[4] += b2f_lo(v.z); a[5] += b2f_hi(v.z);
  a[6] += b2f_lo(v.w); a[7] += b2f_hi(v.w);
}

// ---- gather aggregation: mean of in-neighbor rows, bf16 in/out, f32 accum ----
// 256 threads = 16 groups of 16 lanes; group handles one node; lane covers 8 feats (16B).
// Edge loop unrolled x4 for memory-level parallelism.
__global__ void k_aggregate(const uint4* __restrict__ feat4, const int* __restrict__ rowptr,
                            const int* __restrict__ colsrc, const float* __restrict__ invdeg,
                            uint4* __restrict__ out4, int N) {
  int g = threadIdx.x >> 4, l = threadIdx.x & 15;
  int node = blockIdx.x * 16 + g;
  if (node >= N) return;
  int beg = rowptr[node], end = rowptr[node + 1];
  float a[8] = {0.f, 0.f, 0.f, 0.f, 0.f, 0.f, 0.f, 0.f};
  int e = beg;
  for (; e + 4 <= end; e += 4) {
    int s0 = colsrc[e], s1 = colsrc[e + 1], s2 = colsrc[e + 2], s3 = colsrc[e + 3];
    uint4 v0 = feat4[(size_t)s0 * 16 + l];
    uint4 v1 = feat4[(size_t)s1 * 16 + l];
    uint4 v2 = feat4[(size_t)s2 * 16 + l];
    uint4 v3 = feat4[(size_t)s3 * 16 + l];
    acc8(a, v0); acc8(a, v1); acc8(a, v2); acc8(a, v3);
  }
  for (; e < end; ++e) {
    uint4 v = feat4[(size_t)colsrc[e] * 16 + l];
    acc8(a, v);
  }
  float sc = invdeg[node];
  uint4 o;
  o.x = (unsigned)f2b(a[0] * sc) | ((unsigned)f2b(a[1] * sc) << 16);
  o.y = (unsigned)f2b(a[2] * sc) | ((unsigned)f2b(a[3] * sc) << 16);
  o.z = (unsigned)f2b(a[4] * sc) | ((unsigned)f2b(a[5] * sc) << 16);
  o.w = (unsigned)f2b(a[6] * sc) | ((unsigned)f2b(a[7] * sc) << 16);
  out4[(size_t)node * 16 + l] = o;
}

// ---- GEMM: out[i][:] = self[i]@Wself + neigh[i]@Wneigh + b, optional relu ----
// K=256 combined (ksteps 0-3 from self, 4-7 from neigh). 4 waves x 16 rows x 128 cols.
template <int RELU, int OUTF32>
__global__ void k_gemm(const ushort* __restrict__ selfb, const ushort* __restrict__ neighb,
                       const ushort* __restrict__ Wp, const float* __restrict__ bias,
                       void* __restrict__ outp, int M) {
  int wave = threadIdx.x >> 6, lane = threadIdx.x & 63;
  int rowA = blockIdx.x * 64 + wave * 16 + (lane & 15);
  int kq = lane >> 4;
  bool valid = rowA < M;
  size_t abase = (size_t)rowA * DH + kq * 8;
  f32x4 acc[8] = {};
#pragma unroll
  for (int hf = 0; hf < 2; ++hf) {
    const ushort* S = hf ? neighb : selfb;
#pragma unroll
    for (int ks = 0; ks < 4; ++ks) {
      bf16x8 a = {};
      if (valid) a = __builtin_bit_cast(bf16x8, *(const uint4*)(S + abase + ks * 32));
      int sg = hf * 4 + ks;
      const ushort* wp = Wp + sg * 4096 + lane * 8;
#pragma unroll
      for (int cb = 0; cb < 8; ++cb) {
        bf16x8 b = __builtin_bit_cast(bf16x8, *(const uint4*)(wp + cb * 512));
        acc[cb] = __builtin_amdgcn_mfma_f32_16x16x32_bf16(a, b, acc[cb], 0, 0, 0);
      }
    }
  }
  // C/D layout: col = lane&15, row = (lane>>4)*4 + reg
  int col = lane & 15;
  int row0 = blockIdx.x * 64 + wave * 16 + (lane >> 4) * 4;
#pragma unroll
  for (int cb = 0; cb < 8; ++cb) {
    float bv = bias[cb * 16 + col];
#pragma unroll
    for (int j = 0; j < 4; ++j) {
      int rr = row0 + j;
      if (rr < M) {
        float v = acc[cb][j] + bv;
        if (RELU) v = fmaxf(v, 0.f);
        if (OUTF32)
          ((float*)outp)[(size_t)rr * DH + cb * 16 + col] = v;
        else
          ((ushort*)outp)[(size_t)rr * DH + cb * 16 + col] = f2b(v);
      }
    }
  }
}

extern "C" void kernel_launch(void* const* d_in, const int* in_sizes, int n_in,
                              void* d_out, int out_size, void* d_ws, size_t ws_size,
                              hipStream_t stream) {
  const float* x = (const float*)d_in[0];
  const int* src = (const int*)d_in[1];
  const int* dst = (const int*)d_in[2];
  const float* Wself1 = (const float*)d_in[3];
  const float* Wneigh1 = (const float*)d_in[4];
  const float* b1 = (const float*)d_in[5];
  const float* Wself2 = (const float*)d_in[6];
  const float* Wneigh2 = (const float*)d_in[7];
  const float* b2 = (const float*)d_in[8];
  int N = in_sizes[0] / DH;
  int E = in_sizes[1];

  char* w = (char*)d_ws;
  auto alloc = [&](size_t bytes) {
    char* p = w;
    w += (bytes + 255) & ~(size_t)255;
    return p;
  };
  ushort* xb = (ushort*)alloc((size_t)N * DH * 2);
  ushort* hb = (ushort*)alloc((size_t)N * DH * 2);
  ushort* nb = (ushort*)alloc((size_t)N * DH * 2);
  ushort* Wp1 = (ushort*)alloc(32768 * 2);
  ushort* Wp2 = (ushort*)alloc(32768 * 2);
  int* deg = (int*)alloc((size_t)N * 4);
  int* rowptr = (int*)alloc((size_t)(N + 1) * 4);
  int* cursor = (int*)alloc((size_t)N * 4);
  float* invdeg = (float*)alloc((size_t)N * 4);
  int* colsrc = (int*)alloc((size_t)E * 4);
  int* bsum = (int*)alloc(4096);

  hipMemsetAsync(deg, 0, (size_t)N * 4, stream);

  long n8 = (long)N * DH / 8;
  k_convert<<<(int)((n8 + 255) / 256), 256, 0, stream>>>(x, xb, n8);
  k_pack<<<256, 256, 0, stream>>>(Wself1, Wneigh1, Wself2, Wneigh2, Wp1, Wp2);
  k_hist<<<(E + 255) / 256, 256, 0, stream>>>(dst, deg, E);
  int nb1k = (N + 1023) / 1024;
  k_scan1<<<nb1k, 1024, 0, stream>>>(deg, rowptr, bsum, N);
  k_scan2<<<1, 64, 0, stream>>>(bsum, nb1k);
  k_scan3<<<nb1k, 1024, 0, stream>>>(rowptr, bsum, deg, cursor, invdeg, N);
  k_fill<<<(E + 255) / 256, 256, 0, stream>>>(src, dst, cursor, colsrc, E);

  int aggb = (N + 15) / 16;
  int gb = (N + 63) / 64;
  // layer 1
  k_aggregate<<<aggb, 256, 0, stream>>>((const uint4*)xb, rowptr, colsrc, invdeg, (uint4*)nb, N);
  k_gemm<1, 0><<<gb, 256, 0, stream>>>(xb, nb, Wp1, b1, hb, N);
  // layer 2
  k_aggregate<<<aggb, 256, 0, stream>>>((const uint4*)hb, rowptr, colsrc, invdeg, (uint4*)nb, N);
  k_gemm<0, 1><<<gb, 256, 0, stream>>>(hb, nb, Wp2, b2, d_out, N);
}

// Round 3
// 192.861 us; speedup vs baseline: 1.3773x; 1.0630x over previous
//
#include <hip/hip_runtime.h>

#define DH 128

typedef __bf16 bf16x8 __attribute__((ext_vector_type(8)));
typedef float f32x4 __attribute__((ext_vector_type(4)));

__device__ __forceinline__ ushort f2b(float f) {
  union { float f; unsigned u; } c; c.f = f;
  unsigned u = c.u;
  unsigned r = (u + 0x7fffu + ((u >> 16) & 1u)) >> 16;
  return (ushort)r;
}
__device__ __forceinline__ float b2f_lo(unsigned v) {
  union { unsigned u; float f; } c; c.u = v << 16;
  return c.f;
}
__device__ __forceinline__ float b2f_hi(unsigned v) {
  union { unsigned u; float f; } c; c.u = v & 0xffff0000u;
  return c.f;
}

// ---- fused: convert f32->bf16 (blocks < nConv) + weight pack (rest) ----
// pack: Wp[((s*8+cb)*64+lane)*8 + j] = W[k][col], col = cb*16+(lane&15), k = s*32+(lane>>4)*8+j
__global__ void k_prep0(const float* __restrict__ x, ushort* __restrict__ xb, long n8,
                        int nConv,
                        const float* __restrict__ Ws1, const float* __restrict__ Wn1,
                        const float* __restrict__ Ws2, const float* __restrict__ Wn2,
                        ushort* __restrict__ Wp1, ushort* __restrict__ Wp2) {
  if ((int)blockIdx.x < nConv) {
    long i = (long)blockIdx.x * blockDim.x + threadIdx.x;
    if (i >= n8) return;
    const float4* p = (const float4*)x + i * 2;
    float4 a = p[0], b = p[1];
    uint4 o;
    o.x = (unsigned)f2b(a.x) | ((unsigned)f2b(a.y) << 16);
    o.y = (unsigned)f2b(a.z) | ((unsigned)f2b(a.w) << 16);
    o.z = (unsigned)f2b(b.x) | ((unsigned)f2b(b.y) << 16);
    o.w = (unsigned)f2b(b.z) | ((unsigned)f2b(b.w) << 16);
    ((uint4*)xb)[i] = o;
  } else {
    int idx = (blockIdx.x - nConv) * 256 + threadIdx.x;
    if (idx >= 2 * 8 * 8 * 64 * 8) return;
    int layer = idx >> 15;
    int t = idx & 32767;
    int j = t & 7;
    int lane = (t >> 3) & 63;
    int cb = (t >> 9) & 7;
    int s = (t >> 12) & 7;
    int col = cb * 16 + (lane & 15);
    int k = s * 32 + ((lane >> 4) * 8) + j;
    const float* Wself = layer ? Ws2 : Ws1;
    const float* Wneigh = layer ? Wn2 : Wn1;
    float v = (k < 128) ? Wself[k * 128 + col] : Wneigh[(k - 128) * 128 + col];
    (layer ? Wp2 : Wp1)[t] = f2b(v);
  }
}

// ---- degree histogram, XCD-partitioned by dst range ----
// block b: edge chunk b>>3, node range (b&7). Round-robin block->XCD keeps each
// deg slice resident in one XCD's L2 (no cross-XCD atomic line ping-pong).
__global__ void k_hist8(const int* __restrict__ dst, int* __restrict__ deg,
                        int E, int nper, int chunkSz) {
  int part = blockIdx.x & 7;
  int chunk = blockIdx.x >> 3;
  int lo = part * nper, hi = lo + nper;
  int base = chunk * chunkSz;
  int end = min(base + chunkSz, E);
  for (int i = base + threadIdx.x; i < end; i += 256) {
    int d = dst[i];
    if (d >= lo && d < hi) atomicAdd(&deg[d], 1);
  }
}

// ---- block-level inclusive scan (1024/block) ----
__global__ void k_scan1(const int* __restrict__ deg, int* __restrict__ rowptr,
                        int* __restrict__ bsum, int N) {
  __shared__ int s[1024];
  int t = threadIdx.x, i = blockIdx.x * 1024 + t;
  int v = (i < N) ? deg[i] : 0;
  s[t] = v;
  __syncthreads();
  for (int off = 1; off < 1024; off <<= 1) {
    int u = (t >= off) ? s[t - off] : 0;
    __syncthreads();
    s[t] += u;
    __syncthreads();
  }
  if (i < N) rowptr[i + 1] = s[t];
  if (t == 1023) bsum[blockIdx.x] = s[1023];
}

// ---- exclusive scan of block sums: one wave shfl scan (nb <= 64 fast path) ----
__global__ void k_scan2(int* bsum, int nb) {
  if (nb <= 64) {
    int l = threadIdx.x;
    int v = (l < nb) ? bsum[l] : 0;
    for (int off = 1; off < 64; off <<= 1) {
      int u = __shfl_up(v, off);
      if (l >= off) v += u;
    }
    int ex = __shfl_up(v, 1);
    if (l == 0) ex = 0;
    if (l < nb) bsum[l] = ex;
  } else if (threadIdx.x == 0) {
    int run = 0;
    for (int i = 0; i < nb; ++i) { int v = bsum[i]; bsum[i] = run; run += v; }
  }
}

// ---- add block offsets + emit cursor (=rowptr[i]) and invdeg ----
__global__ void k_scan3(int* __restrict__ rowptr, const int* __restrict__ bsum,
                        const int* __restrict__ deg, int* __restrict__ cursor,
                        float* __restrict__ invdeg, int N) {
  int i = blockIdx.x * 1024 + threadIdx.x;
  if (i == 0) rowptr[0] = 0;
  if (i < N) {
    int d = deg[i];
    int inc = rowptr[i + 1] + bsum[blockIdx.x];
    rowptr[i + 1] = inc;
    cursor[i] = inc - d;
    invdeg[i] = 1.0f / fmaxf((float)d, 1.0f);
  }
}

// ---- CSR fill, XCD-partitioned by dst range (same scheme as k_hist8) ----
// cursor slice (~25KB) + colsrc slice (~400KB) stay in one XCD's L2: atomics
// stop bouncing and colsrc lines absorb all their scattered 4B writes in L2.
__global__ void k_fill8(const int* __restrict__ src, const int* __restrict__ dst,
                        int* __restrict__ cursor, int* __restrict__ colsrc,
                        int E, int nper, int chunkSz) {
  int part = blockIdx.x & 7;
  int chunk = blockIdx.x >> 3;
  int lo = part * nper, hi = lo + nper;
  int base = chunk * chunkSz;
  int end = min(base + chunkSz, E);
  for (int i = base + threadIdx.x; i < end; i += 256) {
    int d = dst[i];
    int s = src[i];
    if (d >= lo && d < hi) {
      int pos = atomicAdd(&cursor[d], 1);
      colsrc[pos] = s;
    }
  }
}

__device__ __forceinline__ void acc8(float* a, uint4 v) {
  a[0] += b2f_lo(v.x); a[1] += b2f_hi(v.x);
  a[2] += b2f_lo(v.y); a[3] += b2f_hi(v.y);
  a[4] += b2f_lo(v.z); a[5] += b2f_hi(v.z);
  a[6] += b2f_lo(v.w); a[7] += b2f_hi(v.w);
}

// ---- gather aggregation: mean of in-neighbor rows, bf16 in/out, f32 accum ----
// 256 threads = 16 groups of 16 lanes; group handles one node; lane covers 8 feats (16B).
__global__ void k_aggregate(const uint4* __restrict__ feat4, const int* __restrict__ rowptr,
                            const int* __restrict__ colsrc, const float* __restrict__ invdeg,
                            uint4* __restrict__ out4, int N) {
  int g = threadIdx.x >> 4, l = threadIdx.x & 15;
  int node = blockIdx.x * 16 + g;
  if (node >= N) return;
  int beg = rowptr[node], end = rowptr[node + 1];
  float a[8] = {0.f, 0.f, 0.f, 0.f, 0.f, 0.f, 0.f, 0.f};
  int e = beg;
  for (; e + 4 <= end; e += 4) {
    int s0 = colsrc[e], s1 = colsrc[e + 1], s2 = colsrc[e + 2], s3 = colsrc[e + 3];
    uint4 v0 = feat4[(size_t)s0 * 16 + l];
    uint4 v1 = feat4[(size_t)s1 * 16 + l];
    uint4 v2 = feat4[(size_t)s2 * 16 + l];
    uint4 v3 = feat4[(size_t)s3 * 16 + l];
    acc8(a, v0); acc8(a, v1); acc8(a, v2); acc8(a, v3);
  }
  for (; e < end; ++e) {
    uint4 v = feat4[(size_t)colsrc[e] * 16 + l];
    acc8(a, v);
  }
  float sc = invdeg[node];
  uint4 o;
  o.x = (unsigned)f2b(a[0] * sc) | ((unsigned)f2b(a[1] * sc) << 16);
  o.y = (unsigned)f2b(a[2] * sc) | ((unsigned)f2b(a[3] * sc) << 16);
  o.z = (unsigned)f2b(a[4] * sc) | ((unsigned)f2b(a[5] * sc) << 16);
  o.w = (unsigned)f2b(a[6] * sc) | ((unsigned)f2b(a[7] * sc) << 16);
  out4[(size_t)node * 16 + l] = o;
}

// ---- GEMM: out[i][:] = self[i]@Wself + neigh[i]@Wneigh + b, optional relu ----
// K=256 combined (ksteps 0-3 self, 4-7 neigh). 4 waves x 16 rows x 128 cols.
template <int RELU, int OUTF32>
__global__ void k_gemm(const ushort* __restrict__ selfb, const ushort* __restrict__ neighb,
                       const ushort* __restrict__ Wp, const float* __restrict__ bias,
                       void* __restrict__ outp, int M) {
  int wave = threadIdx.x >> 6, lane = threadIdx.x & 63;
  int rowA = blockIdx.x * 64 + wave * 16 + (lane & 15);
  int kq = lane >> 4;
  bool valid = rowA < M;
  size_t abase = (size_t)rowA * DH + kq * 8;
  f32x4 acc[8] = {};
#pragma unroll
  for (int hf = 0; hf < 2; ++hf) {
    const ushort* S = hf ? neighb : selfb;
#pragma unroll
    for (int ks = 0; ks < 4; ++ks) {
      bf16x8 a = {};
      if (valid) a = __builtin_bit_cast(bf16x8, *(const uint4*)(S + abase + ks * 32));
      int sg = hf * 4 + ks;
      const ushort* wp = Wp + sg * 4096 + lane * 8;
#pragma unroll
      for (int cb = 0; cb < 8; ++cb) {
        bf16x8 b = __builtin_bit_cast(bf16x8, *(const uint4*)(wp + cb * 512));
        acc[cb] = __builtin_amdgcn_mfma_f32_16x16x32_bf16(a, b, acc[cb], 0, 0, 0);
      }
    }
  }
  // C/D layout: col = lane&15, row = (lane>>4)*4 + reg
  int col = lane & 15;
  int row0 = blockIdx.x * 64 + wave * 16 + (lane >> 4) * 4;
#pragma unroll
  for (int cb = 0; cb < 8; ++cb) {
    float bv = bias[cb * 16 + col];
#pragma unroll
    for (int j = 0; j < 4; ++j) {
      int rr = row0 + j;
      if (rr < M) {
        float v = acc[cb][j] + bv;
        if (RELU) v = fmaxf(v, 0.f);
        if (OUTF32)
          ((float*)outp)[(size_t)rr * DH + cb * 16 + col] = v;
        else
          ((ushort*)outp)[(size_t)rr * DH + cb * 16 + col] = f2b(v);
      }
    }
  }
}

extern "C" void kernel_launch(void* const* d_in, const int* in_sizes, int n_in,
                              void* d_out, int out_size, void* d_ws, size_t ws_size,
                              hipStream_t stream) {
  const float* x = (const float*)d_in[0];
  const int* src = (const int*)d_in[1];
  const int* dst = (const int*)d_in[2];
  const float* Wself1 = (const float*)d_in[3];
  const float* Wneigh1 = (const float*)d_in[4];
  const float* b1 = (const float*)d_in[5];
  const float* Wself2 = (const float*)d_in[6];
  const float* Wneigh2 = (const float*)d_in[7];
  const float* b2 = (const float*)d_in[8];
  int N = in_sizes[0] / DH;
  int E = in_sizes[1];

  char* w = (char*)d_ws;
  auto alloc = [&](size_t bytes) {
    char* p = w;
    w += (bytes + 255) & ~(size_t)255;
    return p;
  };
  ushort* xb = (ushort*)alloc((size_t)N * DH * 2);
  ushort* hb = (ushort*)alloc((size_t)N * DH * 2);
  ushort* nb = (ushort*)alloc((size_t)N * DH * 2);
  ushort* Wp1 = (ushort*)alloc(32768 * 2);
  ushort* Wp2 = (ushort*)alloc(32768 * 2);
  int* deg = (int*)alloc((size_t)N * 4);
  int* rowptr = (int*)alloc((size_t)(N + 1) * 4);
  int* cursor = (int*)alloc((size_t)N * 4);
  float* invdeg = (float*)alloc((size_t)N * 4);
  int* colsrc = (int*)alloc((size_t)E * 4);
  int* bsum = (int*)alloc(4096);

  hipMemsetAsync(deg, 0, (size_t)N * 4, stream);

  long n8 = (long)N * DH / 8;
  int nConv = (int)((n8 + 255) / 256);
  int nPack = (2 * 8 * 8 * 64 * 8 + 255) / 256;
  k_prep0<<<nConv + nPack, 256, 0, stream>>>(x, xb, n8, nConv,
                                             Wself1, Wneigh1, Wself2, Wneigh2, Wp1, Wp2);

  // XCD-partitioned hist/fill: 256 chunks x 8 node-ranges
  int nper = (N + 7) / 8;
  int nchunk = 256;
  int chunkSz = (E + nchunk - 1) / nchunk;
  k_hist8<<<nchunk * 8, 256, 0, stream>>>(dst, deg, E, nper, chunkSz);

  int nb1k = (N + 1023) / 1024;
  k_scan1<<<nb1k, 1024, 0, stream>>>(deg, rowptr, bsum, N);
  k_scan2<<<1, 64, 0, stream>>>(bsum, nb1k);
  k_scan3<<<nb1k, 1024, 0, stream>>>(rowptr, bsum, deg, cursor, invdeg, N);
  k_fill8<<<nchunk * 8, 256, 0, stream>>>(src, dst, cursor, colsrc, E, nper, chunkSz);

  int aggb = (N + 15) / 16;
  int gb = (N + 63) / 64;
  // layer 1
  k_aggregate<<<aggb, 256, 0, stream>>>((const uint4*)xb, rowptr, colsrc, invdeg, (uint4*)nb, N);
  k_gemm<1, 0><<<gb, 256, 0, stream>>>(xb, nb, Wp1, b1, hb, N);
  // layer 2
  k_aggregate<<<aggb, 256, 0, stream>>>((const uint4*)hb, rowptr, colsrc, invdeg, (uint4*)nb, N);
  k_gemm<0, 1><<<gb, 256, 0, stream>>>(hb, nb, Wp2, b2, d_out, N);
}

// Round 4
// 190.318 us; speedup vs baseline: 1.3957x; 1.0134x over previous
//
#include <hip/hip_runtime.h>

#define DH 128

typedef __bf16 bf16x8 __attribute__((ext_vector_type(8)));
typedef float f32x4 __attribute__((ext_vector_type(4)));

__device__ __forceinline__ ushort f2b(float f) {
  union { float f; unsigned u; } c; c.f = f;
  unsigned u = c.u;
  unsigned r = (u + 0x7fffu + ((u >> 16) & 1u)) >> 16;
  return (ushort)r;
}
__device__ __forceinline__ float b2f_lo(unsigned v) {
  union { unsigned u; float f; } c; c.u = v << 16;
  return c.f;
}
__device__ __forceinline__ float b2f_hi(unsigned v) {
  union { unsigned u; float f; } c; c.u = v & 0xffff0000u;
  return c.f;
}

// ---- zero deg (runtime hipMemsetAsync fill kernel costs 43us for 200KB!) ----
__global__ void k_zero(int4* __restrict__ p, int n4) {
  int i = blockIdx.x * 256 + threadIdx.x;
  if (i < n4) p[i] = int4{0, 0, 0, 0};
}

// ---- fused: convert f32->bf16 | weight pack | degree histogram ----
// Three independent block ranges overlap (BW-bound convert hides latency-bound hist).
// pack: Wp[((s*8+cb)*64+lane)*8 + j] = W[k][col], col = cb*16+(lane&15), k = s*32+(lane>>4)*8+j
// hist: block b -> edge chunk (b>>3), dst range (b&7); round-robin block->XCD keeps
//       each deg slice in one XCD's L2 (no cross-XCD atomic line ping-pong).
__global__ void k_prep0(const float* __restrict__ x, ushort* __restrict__ xb, long n8,
                        int nConv, int nPack,
                        const float* __restrict__ Ws1, const float* __restrict__ Wn1,
                        const float* __restrict__ Ws2, const float* __restrict__ Wn2,
                        ushort* __restrict__ Wp1, ushort* __restrict__ Wp2,
                        const int* __restrict__ dst, int* __restrict__ deg,
                        int E, int nper, int chunkSz) {
  int bid = blockIdx.x;
  if (bid < nConv) {
    long i = (long)bid * 256 + threadIdx.x;
    if (i >= n8) return;
    const float4* p = (const float4*)x + i * 2;
    float4 a = p[0], b = p[1];
    uint4 o;
    o.x = (unsigned)f2b(a.x) | ((unsigned)f2b(a.y) << 16);
    o.y = (unsigned)f2b(a.z) | ((unsigned)f2b(a.w) << 16);
    o.z = (unsigned)f2b(b.x) | ((unsigned)f2b(b.y) << 16);
    o.w = (unsigned)f2b(b.z) | ((unsigned)f2b(b.w) << 16);
    ((uint4*)xb)[i] = o;
  } else if (bid < nConv + nPack) {
    int idx = (bid - nConv) * 256 + threadIdx.x;
    if (idx >= 2 * 8 * 8 * 64 * 8) return;
    int layer = idx >> 15;
    int t = idx & 32767;
    int j = t & 7;
    int lane = (t >> 3) & 63;
    int cb = (t >> 9) & 7;
    int s = (t >> 12) & 7;
    int col = cb * 16 + (lane & 15);
    int k = s * 32 + ((lane >> 4) * 8) + j;
    const float* Wself = layer ? Ws2 : Ws1;
    const float* Wneigh = layer ? Wn2 : Wn1;
    float v = (k < 128) ? Wself[k * 128 + col] : Wneigh[(k - 128) * 128 + col];
    (layer ? Wp2 : Wp1)[t] = f2b(v);
  } else {
    int hb = bid - nConv - nPack;
    int part = hb & 7;
    int chunk = hb >> 3;
    int lo = part * nper, hi = lo + nper;
    int base = chunk * chunkSz;
    int end = min(base + chunkSz, E);
    for (int i = base + threadIdx.x; i < end; i += 256) {
      int d = dst[i];
      if (d >= lo && d < hi) atomicAdd(&deg[d], 1);
    }
  }
}

// ---- block-level inclusive scan (1024/block) ----
__global__ void k_scan1(const int* __restrict__ deg, int* __restrict__ rowptr,
                        int* __restrict__ bsum, int N) {
  __shared__ int s[1024];
  int t = threadIdx.x, i = blockIdx.x * 1024 + t;
  int v = (i < N) ? deg[i] : 0;
  s[t] = v;
  __syncthreads();
  for (int off = 1; off < 1024; off <<= 1) {
    int u = (t >= off) ? s[t - off] : 0;
    __syncthreads();
    s[t] += u;
    __syncthreads();
  }
  if (i < N) rowptr[i + 1] = s[t];
  if (t == 1023) bsum[blockIdx.x] = s[1023];
}

// ---- exclusive scan of block sums: one wave shfl scan (nb <= 64 fast path) ----
__global__ void k_scan2(int* bsum, int nb) {
  if (nb <= 64) {
    int l = threadIdx.x;
    int v = (l < nb) ? bsum[l] : 0;
    for (int off = 1; off < 64; off <<= 1) {
      int u = __shfl_up(v, off);
      if (l >= off) v += u;
    }
    int ex = __shfl_up(v, 1);
    if (l == 0) ex = 0;
    if (l < nb) bsum[l] = ex;
  } else if (threadIdx.x == 0) {
    int run = 0;
    for (int i = 0; i < nb; ++i) { int v = bsum[i]; bsum[i] = run; run += v; }
  }
}

// ---- add block offsets + emit cursor (=rowptr[i]) and invdeg ----
__global__ void k_scan3(int* __restrict__ rowptr, const int* __restrict__ bsum,
                        const int* __restrict__ deg, int* __restrict__ cursor,
                        float* __restrict__ invdeg, int N) {
  int i = blockIdx.x * 1024 + threadIdx.x;
  if (i == 0) rowptr[0] = 0;
  if (i < N) {
    int d = deg[i];
    int inc = rowptr[i + 1] + bsum[blockIdx.x];
    rowptr[i + 1] = inc;
    cursor[i] = inc - d;
    invdeg[i] = 1.0f / fmaxf((float)d, 1.0f);
  }
}

// ---- CSR fill, XCD-partitioned by dst range (same scheme as hist) ----
__global__ void k_fill8(const int* __restrict__ src, const int* __restrict__ dst,
                        int* __restrict__ cursor, int* __restrict__ colsrc,
                        int E, int nper, int chunkSz) {
  int part = blockIdx.x & 7;
  int chunk = blockIdx.x >> 3;
  int lo = part * nper, hi = lo + nper;
  int base = chunk * chunkSz;
  int end = min(base + chunkSz, E);
  for (int i = base + threadIdx.x; i < end; i += 256) {
    int d = dst[i];
    int s = src[i];
    if (d >= lo && d < hi) {
      int pos = atomicAdd(&cursor[d], 1);
      colsrc[pos] = s;
    }
  }
}

__device__ __forceinline__ void acc8(float* a, uint4 v) {
  a[0] += b2f_lo(v.x); a[1] += b2f_hi(v.x);
  a[2] += b2f_lo(v.y); a[3] += b2f_hi(v.y);
  a[4] += b2f_lo(v.z); a[5] += b2f_hi(v.z);
  a[6] += b2f_lo(v.w); a[7] += b2f_hi(v.w);
}

// ---- gather aggregation: mean of in-neighbor rows, bf16 in/out, f32 accum ----
// 256 threads = 16 groups of 16 lanes; group handles one node; lane covers 8 feats (16B).
__global__ void k_aggregate(const uint4* __restrict__ feat4, const int* __restrict__ rowptr,
                            const int* __restrict__ colsrc, const float* __restrict__ invdeg,
                            uint4* __restrict__ out4, int N) {
  int g = threadIdx.x >> 4, l = threadIdx.x & 15;
  int node = blockIdx.x * 16 + g;
  if (node >= N) return;
  int beg = rowptr[node], end = rowptr[node + 1];
  float a[8] = {0.f, 0.f, 0.f, 0.f, 0.f, 0.f, 0.f, 0.f};
  int e = beg;
  for (; e + 4 <= end; e += 4) {
    int s0 = colsrc[e], s1 = colsrc[e + 1], s2 = colsrc[e + 2], s3 = colsrc[e + 3];
    uint4 v0 = feat4[(size_t)s0 * 16 + l];
    uint4 v1 = feat4[(size_t)s1 * 16 + l];
    uint4 v2 = feat4[(size_t)s2 * 16 + l];
    uint4 v3 = feat4[(size_t)s3 * 16 + l];
    acc8(a, v0); acc8(a, v1); acc8(a, v2); acc8(a, v3);
  }
  for (; e < end; ++e) {
    uint4 v = feat4[(size_t)colsrc[e] * 16 + l];
    acc8(a, v);
  }
  float sc = invdeg[node];
  uint4 o;
  o.x = (unsigned)f2b(a[0] * sc) | ((unsigned)f2b(a[1] * sc) << 16);
  o.y = (unsigned)f2b(a[2] * sc) | ((unsigned)f2b(a[3] * sc) << 16);
  o.z = (unsigned)f2b(a[4] * sc) | ((unsigned)f2b(a[5] * sc) << 16);
  o.w = (unsigned)f2b(a[6] * sc) | ((unsigned)f2b(a[7] * sc) << 16);
  out4[(size_t)node * 16 + l] = o;
}

// ---- GEMM: out[i][:] = self[i]@Wself + neigh[i]@Wneigh + b, optional relu ----
// K=256 combined (ksteps 0-3 self, 4-7 neigh). 4 waves x 16 rows x 128 cols.
template <int RELU, int OUTF32>
__global__ void k_gemm(const ushort* __restrict__ selfb, const ushort* __restrict__ neighb,
                       const ushort* __restrict__ Wp, const float* __restrict__ bias,
                       void* __restrict__ outp, int M) {
  int wave = threadIdx.x >> 6, lane = threadIdx.x & 63;
  int rowA = blockIdx.x * 64 + wave * 16 + (lane & 15);
  int kq = lane >> 4;
  bool valid = rowA < M;
  size_t abase = (size_t)rowA * DH + kq * 8;
  f32x4 acc[8] = {};
#pragma unroll
  for (int hf = 0; hf < 2; ++hf) {
    const ushort* S = hf ? neighb : selfb;
#pragma unroll
    for (int ks = 0; ks < 4; ++ks) {
      bf16x8 a = {};
      if (valid) a = __builtin_bit_cast(bf16x8, *(const uint4*)(S + abase + ks * 32));
      int sg = hf * 4 + ks;
      const ushort* wp = Wp + sg * 4096 + lane * 8;
#pragma unroll
      for (int cb = 0; cb < 8; ++cb) {
        bf16x8 b = __builtin_bit_cast(bf16x8, *(const uint4*)(wp + cb * 512));
        acc[cb] = __builtin_amdgcn_mfma_f32_16x16x32_bf16(a, b, acc[cb], 0, 0, 0);
      }
    }
  }
  // C/D layout: col = lane&15, row = (lane>>4)*4 + reg
  int col = lane & 15;
  int row0 = blockIdx.x * 64 + wave * 16 + (lane >> 4) * 4;
#pragma unroll
  for (int cb = 0; cb < 8; ++cb) {
    float bv = bias[cb * 16 + col];
#pragma unroll
    for (int j = 0; j < 4; ++j) {
      int rr = row0 + j;
      if (rr < M) {
        float v = acc[cb][j] + bv;
        if (RELU) v = fmaxf(v, 0.f);
        if (OUTF32)
          ((float*)outp)[(size_t)rr * DH + cb * 16 + col] = v;
        else
          ((ushort*)outp)[(size_t)rr * DH + cb * 16 + col] = f2b(v);
      }
    }
  }
}

extern "C" void kernel_launch(void* const* d_in, const int* in_sizes, int n_in,
                              void* d_out, int out_size, void* d_ws, size_t ws_size,
                              hipStream_t stream) {
  const float* x = (const float*)d_in[0];
  const int* src = (const int*)d_in[1];
  const int* dst = (const int*)d_in[2];
  const float* Wself1 = (const float*)d_in[3];
  const float* Wneigh1 = (const float*)d_in[4];
  const float* b1 = (const float*)d_in[5];
  const float* Wself2 = (const float*)d_in[6];
  const float* Wneigh2 = (const float*)d_in[7];
  const float* b2 = (const float*)d_in[8];
  int N = in_sizes[0] / DH;
  int E = in_sizes[1];

  char* w = (char*)d_ws;
  auto alloc = [&](size_t bytes) {
    char* p = w;
    w += (bytes + 255) & ~(size_t)255;
    return p;
  };
  ushort* xb = (ushort*)alloc((size_t)N * DH * 2);
  ushort* hb = (ushort*)alloc((size_t)N * DH * 2);
  ushort* nb = (ushort*)alloc((size_t)N * DH * 2);
  ushort* Wp1 = (ushort*)alloc(32768 * 2);
  ushort* Wp2 = (ushort*)alloc(32768 * 2);
  int* deg = (int*)alloc((size_t)N * 4);
  int* rowptr = (int*)alloc((size_t)(N + 1) * 4);
  int* cursor = (int*)alloc((size_t)N * 4);
  float* invdeg = (float*)alloc((size_t)N * 4);
  int* colsrc = (int*)alloc((size_t)E * 4);
  int* bsum = (int*)alloc(4096);

  // zero deg with our own kernel (runtime fill kernel takes 43us for 200KB)
  int n4 = (N + 3) / 4;
  k_zero<<<(n4 + 255) / 256, 256, 0, stream>>>((int4*)deg, n4);

  long n8 = (long)N * DH / 8;
  int nConv = (int)((n8 + 255) / 256);
  int nPack = (2 * 8 * 8 * 64 * 8 + 255) / 256;
  int nper = (N + 7) / 8;
  int nchunk = 256;
  int chunkSz = (E + nchunk - 1) / nchunk;
  int nHist = nchunk * 8;
  k_prep0<<<nConv + nPack + nHist, 256, 0, stream>>>(
      x, xb, n8, nConv, nPack, Wself1, Wneigh1, Wself2, Wneigh2, Wp1, Wp2,
      dst, deg, E, nper, chunkSz);

  int nb1k = (N + 1023) / 1024;
  k_scan1<<<nb1k, 1024, 0, stream>>>(deg, rowptr, bsum, N);
  k_scan2<<<1, 64, 0, stream>>>(bsum, nb1k);
  k_scan3<<<nb1k, 1024, 0, stream>>>(rowptr, bsum, deg, cursor, invdeg, N);
  k_fill8<<<nchunk * 8, 256, 0, stream>>>(src, dst, cursor, colsrc, E, nper, chunkSz);

  int aggb = (N + 15) / 16;
  int gb = (N + 63) / 64;
  // layer 1
  k_aggregate<<<aggb, 256, 0, stream>>>((const uint4*)xb, rowptr, colsrc, invdeg, (uint4*)nb, N);
  k_gemm<1, 0><<<gb, 256, 0, stream>>>(xb, nb, Wp1, b1, hb, N);
  // layer 2
  k_aggregate<<<aggb, 256, 0, stream>>>((const uint4*)hb, rowptr, colsrc, invdeg, (uint4*)nb, N);
  k_gemm<0, 1><<<gb, 256, 0, stream>>>(hb, nb, Wp2, b2, d_out, N);
}

// Round 5
// 190.061 us; speedup vs baseline: 1.3976x; 1.0013x over previous
//
#include <hip/hip_runtime.h>

#define DH 128

typedef __bf16 bf16x8 __attribute__((ext_vector_type(8)));
typedef float f32x4 __attribute__((ext_vector_type(4)));

__device__ __forceinline__ ushort f2b(float f) {
  union { float f; unsigned u; } c; c.f = f;
  unsigned u = c.u;
  unsigned r = (u + 0x7fffu + ((u >> 16) & 1u)) >> 16;
  return (ushort)r;
}
__device__ __forceinline__ float b2f_lo(unsigned v) {
  union { unsigned u; float f; } c; c.u = v << 16;
  return c.f;
}
__device__ __forceinline__ float b2f_hi(unsigned v) {
  union { unsigned u; float f; } c; c.u = v & 0xffff0000u;
  return c.f;
}

// ---- zero deg (runtime hipMemsetAsync fill kernel costs 43us for 200KB!) ----
__global__ void k_zero(int4* __restrict__ p, int n4) {
  int i = blockIdx.x * 256 + threadIdx.x;
  if (i < n4) p[i] = int4{0, 0, 0, 0};
}

// ---- fused: convert f32->bf16 | weight pack (NO hist here: streaming traffic
// evicts deg lines from L2 and turns every atomic into an HBM round-trip) ----
__global__ void k_prep0(const float* __restrict__ x, ushort* __restrict__ xb, long n8,
                        int nConv,
                        const float* __restrict__ Ws1, const float* __restrict__ Wn1,
                        const float* __restrict__ Ws2, const float* __restrict__ Wn2,
                        ushort* __restrict__ Wp1, ushort* __restrict__ Wp2) {
  int bid = blockIdx.x;
  if (bid < nConv) {
    long i = (long)bid * 256 + threadIdx.x;
    if (i >= n8) return;
    const float4* p = (const float4*)x + i * 2;
    float4 a = p[0], b = p[1];
    uint4 o;
    o.x = (unsigned)f2b(a.x) | ((unsigned)f2b(a.y) << 16);
    o.y = (unsigned)f2b(a.z) | ((unsigned)f2b(a.w) << 16);
    o.z = (unsigned)f2b(b.x) | ((unsigned)f2b(b.y) << 16);
    o.w = (unsigned)f2b(b.z) | ((unsigned)f2b(b.w) << 16);
    ((uint4*)xb)[i] = o;
  } else {
    int idx = (bid - nConv) * 256 + threadIdx.x;
    if (idx >= 2 * 8 * 8 * 64 * 8) return;
    int layer = idx >> 15;
    int t = idx & 32767;
    int j = t & 7;
    int lane = (t >> 3) & 63;
    int cb = (t >> 9) & 7;
    int s = (t >> 12) & 7;
    int col = cb * 16 + (lane & 15);
    int k = s * 32 + ((lane >> 4) * 8) + j;
    const float* Wself = layer ? Ws2 : Ws1;
    const float* Wneigh = layer ? Wn2 : Wn1;
    float v = (k < 128) ? Wself[k * 128 + col] : Wneigh[(k - 128) * 128 + col];
    (layer ? Wp2 : Wp1)[t] = f2b(v);
  }
}

// ---- degree histogram, XCD-partitioned by dst range ----
__global__ void k_hist8(const int* __restrict__ dst, int* __restrict__ deg,
                        int E, int nper, int chunkSz) {
  int part = blockIdx.x & 7;
  int chunk = blockIdx.x >> 3;
  int lo = part * nper, hi = lo + nper;
  int base = chunk * chunkSz;
  int end = min(base + chunkSz, E);
  for (int i = base + threadIdx.x; i < end; i += 256) {
    int d = dst[i];
    if (d >= lo && d < hi) atomicAdd(&deg[d], 1);
  }
}

// ---- block-level inclusive scan (1024/block) ----
__global__ void k_scan1(const int* __restrict__ deg, int* __restrict__ rowptr,
                        int* __restrict__ bsum, int N) {
  __shared__ int s[1024];
  int t = threadIdx.x, i = blockIdx.x * 1024 + t;
  int v = (i < N) ? deg[i] : 0;
  s[t] = v;
  __syncthreads();
  for (int off = 1; off < 1024; off <<= 1) {
    int u = (t >= off) ? s[t - off] : 0;
    __syncthreads();
    s[t] += u;
    __syncthreads();
  }
  if (i < N) rowptr[i + 1] = s[t];
  if (t == 1023) bsum[blockIdx.x] = s[1023];
}

// ---- exclusive scan of block sums: one wave shfl scan (nb <= 64 fast path) ----
__global__ void k_scan2(int* bsum, int nb) {
  if (nb <= 64) {
    int l = threadIdx.x;
    int v = (l < nb) ? bsum[l] : 0;
    for (int off = 1; off < 64; off <<= 1) {
      int u = __shfl_up(v, off);
      if (l >= off) v += u;
    }
    int ex = __shfl_up(v, 1);
    if (l == 0) ex = 0;
    if (l < nb) bsum[l] = ex;
  } else if (threadIdx.x == 0) {
    int run = 0;
    for (int i = 0; i < nb; ++i) { int v = bsum[i]; bsum[i] = run; run += v; }
  }
}

// ---- add block offsets + emit cursor (=rowptr[i]) and invdeg ----
__global__ void k_scan3(int* __restrict__ rowptr, const int* __restrict__ bsum,
                        const int* __restrict__ deg, int* __restrict__ cursor,
                        float* __restrict__ invdeg, int N) {
  int i = blockIdx.x * 1024 + threadIdx.x;
  if (i == 0) rowptr[0] = 0;
  if (i < N) {
    int d = deg[i];
    int inc = rowptr[i + 1] + bsum[blockIdx.x];
    rowptr[i + 1] = inc;
    cursor[i] = inc - d;
    invdeg[i] = 1.0f / fmaxf((float)d, 1.0f);
  }
}

// ---- CSR fill, XCD-partitioned by dst range ----
__global__ void k_fill8(const int* __restrict__ src, const int* __restrict__ dst,
                        int* __restrict__ cursor, int* __restrict__ colsrc,
                        int E, int nper, int chunkSz) {
  int part = blockIdx.x & 7;
  int chunk = blockIdx.x >> 3;
  int lo = part * nper, hi = lo + nper;
  int base = chunk * chunkSz;
  int end = min(base + chunkSz, E);
  for (int i = base + threadIdx.x; i < end; i += 256) {
    int d = dst[i];
    int s = src[i];
    if (d >= lo && d < hi) {
      int pos = atomicAdd(&cursor[d], 1);
      colsrc[pos] = s;
    }
  }
}

__device__ __forceinline__ void acc8(float* a, uint4 v) {
  a[0] += b2f_lo(v.x); a[1] += b2f_hi(v.x);
  a[2] += b2f_lo(v.y); a[3] += b2f_hi(v.y);
  a[4] += b2f_lo(v.z); a[5] += b2f_hi(v.z);
  a[6] += b2f_lo(v.w); a[7] += b2f_hi(v.w);
}

// ---- fused aggregate + GEMM per layer ----
// Block = 64 nodes (= GEMM tile), 4 waves.
// Phase 1: wave w aggregates nodes w*16..w*16+15 (16 lanes/node, 8 feats each,
//          x4-unrolled gather), mean -> bf16 -> LDS hn[64][136] (16B-aligned rows).
// Phase 2: GEMM K=256: self half A-frags from global feat, neigh half from LDS.
template <int RELU, int OUTF32>
__global__ void k_aggemm(const ushort* __restrict__ feat, const int* __restrict__ rowptr,
                         const int* __restrict__ colsrc, const float* __restrict__ invdeg,
                         const ushort* __restrict__ Wp, const float* __restrict__ bias,
                         void* __restrict__ outp, int M) {
  __shared__ ushort hn[64][136];
  int wave = threadIdx.x >> 6, lane = threadIdx.x & 63;
  int g = (lane >> 4) & 3, l = lane & 15;
  const uint4* feat4 = (const uint4*)feat;

  // ---- phase 1: aggregation ----
#pragma unroll
  for (int it = 0; it < 4; ++it) {
    int r = wave * 16 + it * 4 + g;
    int node = blockIdx.x * 64 + r;
    float a[8] = {0.f, 0.f, 0.f, 0.f, 0.f, 0.f, 0.f, 0.f};
    float sc = 0.f;
    if (node < M) {
      int beg = rowptr[node], end = rowptr[node + 1];
      int e = beg;
      for (; e + 4 <= end; e += 4) {
        int s0 = colsrc[e], s1 = colsrc[e + 1], s2 = colsrc[e + 2], s3 = colsrc[e + 3];
        uint4 v0 = feat4[(size_t)s0 * 16 + l];
        uint4 v1 = feat4[(size_t)s1 * 16 + l];
        uint4 v2 = feat4[(size_t)s2 * 16 + l];
        uint4 v3 = feat4[(size_t)s3 * 16 + l];
        acc8(a, v0); acc8(a, v1); acc8(a, v2); acc8(a, v3);
      }
      for (; e < end; ++e) acc8(a, feat4[(size_t)colsrc[e] * 16 + l]);
      sc = invdeg[node];
    }
    uint4 o;
    o.x = (unsigned)f2b(a[0] * sc) | ((unsigned)f2b(a[1] * sc) << 16);
    o.y = (unsigned)f2b(a[2] * sc) | ((unsigned)f2b(a[3] * sc) << 16);
    o.z = (unsigned)f2b(a[4] * sc) | ((unsigned)f2b(a[5] * sc) << 16);
    o.w = (unsigned)f2b(a[6] * sc) | ((unsigned)f2b(a[7] * sc) << 16);
    *(uint4*)&hn[r][l * 8] = o;
  }
  __syncthreads();

  // ---- phase 2: GEMM ----
  int rowA = blockIdx.x * 64 + wave * 16 + (lane & 15);
  int kq = lane >> 4;
  bool valid = rowA < M;
  size_t abase = (size_t)rowA * DH + kq * 8;
  int lrow = wave * 16 + (lane & 15);
  f32x4 acc[8] = {};
#pragma unroll
  for (int hf = 0; hf < 2; ++hf) {
#pragma unroll
    for (int ks = 0; ks < 4; ++ks) {
      bf16x8 a = {};
      if (hf == 0) {
        if (valid) a = __builtin_bit_cast(bf16x8, *(const uint4*)(feat + abase + ks * 32));
      } else {
        a = __builtin_bit_cast(bf16x8, *(const uint4*)&hn[lrow][ks * 32 + kq * 8]);
      }
      int sg = hf * 4 + ks;
      const ushort* wp = Wp + sg * 4096 + lane * 8;
#pragma unroll
      for (int cb = 0; cb < 8; ++cb) {
        bf16x8 b = __builtin_bit_cast(bf16x8, *(const uint4*)(wp + cb * 512));
        acc[cb] = __builtin_amdgcn_mfma_f32_16x16x32_bf16(a, b, acc[cb], 0, 0, 0);
      }
    }
  }
  // C/D layout: col = lane&15, row = (lane>>4)*4 + reg
  int col = lane & 15;
  int row0 = blockIdx.x * 64 + wave * 16 + (lane >> 4) * 4;
#pragma unroll
  for (int cb = 0; cb < 8; ++cb) {
    float bv = bias[cb * 16 + col];
#pragma unroll
    for (int j = 0; j < 4; ++j) {
      int rr = row0 + j;
      if (rr < M) {
        float v = acc[cb][j] + bv;
        if (RELU) v = fmaxf(v, 0.f);
        if (OUTF32)
          ((float*)outp)[(size_t)rr * DH + cb * 16 + col] = v;
        else
          ((ushort*)outp)[(size_t)rr * DH + cb * 16 + col] = f2b(v);
      }
    }
  }
}

extern "C" void kernel_launch(void* const* d_in, const int* in_sizes, int n_in,
                              void* d_out, int out_size, void* d_ws, size_t ws_size,
                              hipStream_t stream) {
  const float* x = (const float*)d_in[0];
  const int* src = (const int*)d_in[1];
  const int* dst = (const int*)d_in[2];
  const float* Wself1 = (const float*)d_in[3];
  const float* Wneigh1 = (const float*)d_in[4];
  const float* b1 = (const float*)d_in[5];
  const float* Wself2 = (const float*)d_in[6];
  const float* Wneigh2 = (const float*)d_in[7];
  const float* b2 = (const float*)d_in[8];
  int N = in_sizes[0] / DH;
  int E = in_sizes[1];

  char* w = (char*)d_ws;
  auto alloc = [&](size_t bytes) {
    char* p = w;
    w += (bytes + 255) & ~(size_t)255;
    return p;
  };
  ushort* xb = (ushort*)alloc((size_t)N * DH * 2);
  ushort* hb = (ushort*)alloc((size_t)N * DH * 2);
  ushort* Wp1 = (ushort*)alloc(32768 * 2);
  ushort* Wp2 = (ushort*)alloc(32768 * 2);
  int* deg = (int*)alloc((size_t)N * 4);
  int* rowptr = (int*)alloc((size_t)(N + 1) * 4);
  int* cursor = (int*)alloc((size_t)N * 4);
  float* invdeg = (float*)alloc((size_t)N * 4);
  int* colsrc = (int*)alloc((size_t)E * 4);
  int* bsum = (int*)alloc(4096);

  int n4 = (N + 3) / 4;
  k_zero<<<(n4 + 255) / 256, 256, 0, stream>>>((int4*)deg, n4);

  long n8 = (long)N * DH / 8;
  int nConv = (int)((n8 + 255) / 256);
  int nPack = (2 * 8 * 8 * 64 * 8 + 255) / 256;
  k_prep0<<<nConv + nPack, 256, 0, stream>>>(x, xb, n8, nConv,
                                             Wself1, Wneigh1, Wself2, Wneigh2, Wp1, Wp2);

  int nper = (N + 7) / 8;
  int nchunk = 256;
  int chunkSz = (E + nchunk - 1) / nchunk;
  k_hist8<<<nchunk * 8, 256, 0, stream>>>(dst, deg, E, nper, chunkSz);

  int nb1k = (N + 1023) / 1024;
  k_scan1<<<nb1k, 1024, 0, stream>>>(deg, rowptr, bsum, N);
  k_scan2<<<1, 64, 0, stream>>>(bsum, nb1k);
  k_scan3<<<nb1k, 1024, 0, stream>>>(rowptr, bsum, deg, cursor, invdeg, N);
  k_fill8<<<nchunk * 8, 256, 0, stream>>>(src, dst, cursor, colsrc, E, nper, chunkSz);

  int gb = (N + 63) / 64;
  k_aggemm<1, 0><<<gb, 256, 0, stream>>>(xb, rowptr, colsrc, invdeg, Wp1, b1, hb, N);
  k_aggemm<0, 1><<<gb, 256, 0, stream>>>(hb, rowptr, colsrc, invdeg, Wp2, b2, d_out, N);
}